// Round 12
// baseline (15790.038 us; speedup 1.0000x reference)
//
#include <hip/hip_runtime.h>

#define BB 256
#define TT 256
#define II 256
#define HH 1024
#define LL 128
#define K1 1280   // HH + II
#define GN 3072   // 3*HH
#define BBHH (BB * HH)

#define RP2 97    // red row stride (floats)
#define GP2 33    // gxn row stride
#define PP 20     // pred row stride

typedef short s8v    __attribute__((ext_vector_type(8)));
typedef float f32x4  __attribute__((ext_vector_type(4)));
typedef float f4v    __attribute__((ext_vector_type(4)));
typedef unsigned long long u64;
typedef unsigned short us;

__device__ __forceinline__ us f2bf(float f) {
    unsigned u = __float_as_uint(f);
    u += 0x7fffu + ((u >> 16) & 1u);
    return (us)(u >> 16);
}
__device__ __forceinline__ float bf2f(us h) {
    return __uint_as_float(((unsigned)h) << 16);
}
__device__ __forceinline__ float sigm(float x) { return 1.0f / (1.0f + __expf(-x)); }

__device__ __forceinline__ s8v cvt8(const float* __restrict__ p) {
    const f4v lo = *(const f4v*)p;
    const f4v hi = *(const f4v*)(p + 4);
    s8v r;
    r[0] = (short)f2bf(lo[0]); r[1] = (short)f2bf(lo[1]);
    r[2] = (short)f2bf(lo[2]); r[3] = (short)f2bf(lo[3]);
    r[4] = (short)f2bf(hi[0]); r[5] = (short)f2bf(hi[1]);
    r[6] = (short)f2bf(hi[2]); r[7] = (short)f2bf(hi[3]);
    return r;
}

// sc1 (coherence-point) 16B load, for the 3-slot fallback
__device__ __forceinline__ s8v hload16a(const us* p) {
    union { u64 q[2]; s8v v; } u;
    u.q[0] = __hip_atomic_load((const u64*)p, __ATOMIC_RELAXED, __HIP_MEMORY_SCOPE_AGENT);
    u.q[1] = __hip_atomic_load((const u64*)p + 1, __ATOMIC_RELAXED, __HIP_MEMORY_SCOPE_AGENT);
    return u.v;
}
template<int FRESH> __device__ __forceinline__ s8v ld16h(const us* p) {
    if constexpr (FRESH) return *(const s8v*)p;
    else return hload16a(p);
}
template<int FRESH> __device__ __forceinline__ u64 ld8h(const us* p) {
    if constexpr (FRESH) return *(const u64*)p;
    else return __hip_atomic_load((const u64*)p, __ATOMIC_RELAXED, __HIP_MEMORY_SCOPE_AGENT);
}
// h stores: sc1 (consumers cross-XCD under nt-major mapping)
__device__ __forceinline__ void h_store8(us* p, u64 v) {
    __hip_atomic_store((u64*)p, v, __ATOMIC_RELAXED, __HIP_MEMORY_SCOPE_AGENT);
}
__device__ __forceinline__ void flag_store(unsigned* p, unsigned v) {
    __hip_atomic_store(p, v, __ATOMIC_RELAXED, __HIP_MEMORY_SCOPE_AGENT);
}
__device__ __forceinline__ unsigned flag_probe(unsigned* p) {
    return __hip_atomic_load(p, __ATOMIC_RELAXED, __HIP_MEMORY_SCOPE_AGENT);
}
// BUSY group barrier: all waves call it; dependent-FMA burst between probes
// keeps the VALU active (DVFS signal) instead of s_sleep idling.
__device__ __forceinline__ void group_wait_busy(unsigned* gf, int lane, unsigned t) {
    if (t == 0) return;
    float busy = (float)lane * 0.015625f + 1.0f;
    int guard = 0;
    for (;;) {
        unsigned v = t;
        if (lane < 32) v = flag_probe(gf + lane);
        if (__ballot(v >= t) == ~0ull) break;
#pragma unroll
        for (int i = 0; i < 64; ++i)
            busy = __builtin_fmaf(busy, 1.0000001f, 1e-9f);
        asm volatile("" :: "v"(busy));   // keep-alive (rule #17)
        if (++guard > (1 << 17)) break;  // safety valve
    }
    asm volatile("" ::: "memory");
}

// ---- prep: permuted gate weights, 96-row blocks per WG (unchanged) ----
__global__ void k_prep_w(const float* __restrict__ Whh, const float* __restrict__ Wih,
                         us* __restrict__ Wperm) {
    int o = blockIdx.x;                 // 3072
    int ntt = o / 96, q = o - ntt * 96;
    int gate = q >> 5, jj = q & 31;
    int src = gate * HH + ntt * 32 + jj;
    const float* sh = Whh + (size_t)src * HH;
    const float* si = Wih + (size_t)src * II;
    us* dst = Wperm + (size_t)o * K1;
    for (int k = threadIdx.x; k < K1; k += 256)
        dst[k] = f2bf(k < HH ? sh[k] : si[k - HH]);
}

__global__ void k_prep_misc(const float* __restrict__ bih, const float* __restrict__ bhh,
                            const float* __restrict__ Wout,
                            float* __restrict__ bihp, float* __restrict__ bhhp,
                            us* __restrict__ Woutb) {
    int idx = blockIdx.x * 256 + threadIdx.x;
    if (idx < GN) {
        int ntt = idx / 96, q = idx - ntt * 96;
        int gate = q >> 5, jj = q & 31;
        int src = gate * HH + ntt * 32 + jj;
        bihp[idx] = bih[src];
        bhhp[idx] = bhh[src];
    }
    for (size_t i = (size_t)blockIdx.x * 256 + threadIdx.x; i < (size_t)II * HH;
         i += (size_t)gridDim.x * 256)
        Woutb[i] = f2bf(Wout[i]);
}

__global__ void k_h0(const float* __restrict__ z, const float* __restrict__ Wz,
                     const float* __restrict__ bz, us* __restrict__ hbuf) {
    int b = blockIdx.x;
    int j0 = threadIdx.x * 4;
    const f4v* zr = (const f4v*)(z + (size_t)b * LL);
    u64 packed = 0;
#pragma unroll
    for (int jj = 0; jj < 4; ++jj) {
        int j = j0 + jj;
        const f4v* wr = (const f4v*)(Wz + (size_t)j * LL);
        float s = bz[j];
#pragma unroll
        for (int i = 0; i < LL / 4; ++i) {
            f4v a = zr[i], w = wr[i];
            s += a[0] * w[0] + a[1] * w[1] + a[2] * w[2] + a[3] * w[3];
        }
        packed |= (u64)f2bf(tanhf(s)) << (16 * jj);
    }
    *(u64*)(hbuf + (size_t)b * HH + j0) = packed;
}

// output projection: one 16x16 tile, K=1024 split across 4 waves
template<int FRESH>
__device__ __forceinline__ void proj_tile(
    const us* hb, const us* __restrict__ Woutb,
    float* __restrict__ out, float (*pred)[16 * PP],
    int brow, int it, int wave, int lane, int lr, int lk, int tp, float boutv) {
    f32x4 oa = {0.f, 0.f, 0.f, 0.f};
    const us* ap = hb + (size_t)(brow + lr) * HH + (wave << 8) + lk;
    const us* wp = Woutb + (size_t)(it * 16 + lr) * HH + (wave << 8) + lk;
#pragma unroll
    for (int ks = 0; ks < 8; ++ks) {
        s8v a = ld16h<FRESH>(ap + ks * 32);
        s8v w = *(const s8v*)(wp + ks * 32);
        oa = __builtin_amdgcn_mfma_f32_16x16x32_bf16(a, w, oa, 0, 0, 0);
    }
    if (wave >= 1) {
#pragma unroll
        for (int r = 0; r < 4; ++r)
            pred[wave - 1][(((lane >> 4) << 2) + r) * PP + lr] = oa[r];
    }
    __syncthreads();
    if (wave == 0) {
#pragma unroll
        for (int r = 0; r < 4; ++r) {
            int rw = ((lane >> 4) << 2) + r;
            int idx = rw * PP + lr;
            float v = oa[r] + pred[0][idx] + pred[1][idx] + pred[2][idx] + boutv;
            out[(size_t)(brow + rw) * (TT * II) + (size_t)tp * II + it * 16 + lr] = sigm(v);
        }
    }
    __syncthreads();
}

// ---- main loop, nt-major XCD mapping (unchanged from round 11) ----
template<int FRESH>
__device__ void run12(const float* __restrict__ tgt, const us* __restrict__ Wperm,
                      const float* __restrict__ bihp, const float* __restrict__ bhhp,
                      us* hbuf, const us* __restrict__ Woutb,
                      const float* __restrict__ bout, float* __restrict__ out,
                      unsigned* flags,
                      float (*red)[32 * RP2], float* gxn, float (*pred)[16 * PP]) {
    const int tid = threadIdx.x;
    const int wave = tid >> 6, lane = tid & 63;
    const int lr = lane & 15;
    const int lk = (lane >> 4) << 3;
    const int hi4 = ((lane >> 4) << 2);
    const int bid = blockIdx.x;
    const int x = bid & 7, q = (bid >> 3) & 3, g = bid >> 5;
    const int nt = x * 4 + q;
    const int bt = nt >> 4, it = nt & 15;
    const int brow = g * 32 + bt * 16;
    const float boutv = bout[it * 16 + lr];

    const int eb = tid & 31, jq = tid >> 5;
    const int ob = nt * 96;
    float bir[4], biz[4], bixn[4], bihn[4];
#pragma unroll
    for (int jj = 0; jj < 4; ++jj) {
        int lj = jq * 4 + jj;
        bir[jj]  = bihp[ob + lj] + bhhp[ob + lj];
        biz[jj]  = bihp[ob + 32 + lj] + bhhp[ob + 32 + lj];
        bixn[jj] = bihp[ob + 64 + lj];
        bihn[jj] = bhhp[ob + 64 + lj];
    }

    unsigned* gflags = flags + (g << 6);

    for (int t = 0; t < TT; ++t) {
        const us* hcur = hbuf + (size_t)(FRESH ? t : (t % 3)) * BBHH;
        us* hnxt = hbuf + (size_t)(FRESH ? (t + 1) : ((t + 1) % 3)) * BBHH;

        f32x4 acc[12];
#pragma unroll
        for (int i = 0; i < 12; ++i) acc[i] = (f32x4){0.f, 0.f, 0.f, 0.f};
        f32x4 accx[4];
#pragma unroll
        for (int i = 0; i < 4; ++i) accx[i] = (f32x4){0.f, 0.f, 0.f, 0.f};

        // wave 3: x-part GEMM BEFORE the barrier (constant X)
        if (wave == 3) {
#pragma unroll
            for (int ks = 0; ks < 8; ++ks) {
                const int k0 = ks * 32 + lk;
                s8v xa[2], w[6];
#pragma unroll
                for (int mi = 0; mi < 2; ++mi)
                    xa[mi] = cvt8(tgt + ((size_t)(g * 32 + mi * 16 + lr) * TT + t) * II + k0);
#pragma unroll
                for (int ni = 0; ni < 6; ++ni)
                    w[ni] = *(const s8v*)(Wperm + (size_t)(ob + ni * 16 + lr) * K1 + HH + k0);
#pragma unroll
                for (int mi = 0; mi < 2; ++mi) {
#pragma unroll
                    for (int ni = 0; ni < 4; ++ni)
                        acc[mi * 6 + ni] = __builtin_amdgcn_mfma_f32_16x16x32_bf16(
                            xa[mi], w[ni], acc[mi * 6 + ni], 0, 0, 0);
                    accx[mi * 2 + 0] = __builtin_amdgcn_mfma_f32_16x16x32_bf16(
                        xa[mi], w[4], accx[mi * 2 + 0], 0, 0, 0);
                    accx[mi * 2 + 1] = __builtin_amdgcn_mfma_f32_16x16x32_bf16(
                        xa[mi], w[5], accx[mi * 2 + 1], 0, 0, 0);
                }
            }
        }

        // barrier: ALL waves busy-poll (DVFS signal + no parked waves)
        group_wait_busy(gflags, lane, (unsigned)t);
        __syncthreads();

        // h-part GEMM
        if (wave < 3) {
#pragma unroll
            for (int ci = 0; ci < 10; ++ci) {
                const int k0 = wave * 320 + ci * 32 + lk;
                s8v a[2], w[6];
#pragma unroll
                for (int mi = 0; mi < 2; ++mi)
                    a[mi] = ld16h<FRESH>(hcur + (size_t)(g * 32 + mi * 16 + lr) * HH + k0);
#pragma unroll
                for (int ni = 0; ni < 6; ++ni)
                    w[ni] = *(const s8v*)(Wperm + (size_t)(ob + ni * 16 + lr) * K1 + k0);
#pragma unroll
                for (int mi = 0; mi < 2; ++mi)
#pragma unroll
                    for (int ni = 0; ni < 6; ++ni)
                        acc[mi * 6 + ni] = __builtin_amdgcn_mfma_f32_16x16x32_bf16(
                            a[mi], w[ni], acc[mi * 6 + ni], 0, 0, 0);
            }
        } else {
#pragma unroll
            for (int ks = 0; ks < 2; ++ks) {
                const int k0 = 960 + ks * 32 + lk;
                s8v a[2], w[6];
#pragma unroll
                for (int mi = 0; mi < 2; ++mi)
                    a[mi] = ld16h<FRESH>(hcur + (size_t)(g * 32 + mi * 16 + lr) * HH + k0);
#pragma unroll
                for (int ni = 0; ni < 6; ++ni)
                    w[ni] = *(const s8v*)(Wperm + (size_t)(ob + ni * 16 + lr) * K1 + k0);
#pragma unroll
                for (int mi = 0; mi < 2; ++mi)
#pragma unroll
                    for (int ni = 0; ni < 6; ++ni)
                        acc[mi * 6 + ni] = __builtin_amdgcn_mfma_f32_16x16x32_bf16(
                            a[mi], w[ni], acc[mi * 6 + ni], 0, 0, 0);
            }
#pragma unroll
            for (int mi = 0; mi < 2; ++mi)
#pragma unroll
                for (int n2 = 0; n2 < 2; ++n2)
#pragma unroll
                    for (int r = 0; r < 4; ++r)
                        gxn[(mi * 16 + hi4 + r) * GP2 + n2 * 16 + lr] = accx[mi * 2 + n2][r];
        }

        // all 4 waves write partials; epilogue sums the 4 sets
        {
            float* s = &red[wave][0];
#pragma unroll
            for (int mi = 0; mi < 2; ++mi)
#pragma unroll
                for (int ni = 0; ni < 6; ++ni)
#pragma unroll
                    for (int r = 0; r < 4; ++r)
                        s[(mi * 16 + hi4 + r) * RP2 + ni * 16 + lr] = acc[mi * 6 + ni][r];
        }
        __syncthreads();

        // gate epilogue: thread (eb, jq*4..+3) -> one 8B sc1 h store
        {
            const int bg = g * 32 + eb;
            const int jbase = nt * 32 + jq * 4;
            u64 hold8 = ld8h<FRESH>(hcur + (size_t)bg * HH + jbase);
            u64 packed = 0;
#pragma unroll
            for (int jj = 0; jj < 4; ++jj) {
                int lj = jq * 4 + jj;
                float ghr = red[0][eb * RP2 + lj] + red[1][eb * RP2 + lj] +
                            red[2][eb * RP2 + lj] + red[3][eb * RP2 + lj];
                float ghz = red[0][eb * RP2 + 32 + lj] + red[1][eb * RP2 + 32 + lj] +
                            red[2][eb * RP2 + 32 + lj] + red[3][eb * RP2 + 32 + lj];
                float ghn = red[0][eb * RP2 + 64 + lj] + red[1][eb * RP2 + 64 + lj] +
                            red[2][eb * RP2 + 64 + lj] + red[3][eb * RP2 + 64 + lj];
                float gx  = gxn[eb * GP2 + lj];
                float r   = sigm(ghr + bir[jj]);
                float zg  = sigm(ghz + biz[jj]);
                float n   = tanhf(gx + bixn[jj] + r * (ghn + bihn[jj]));
                float ho  = bf2f((us)(hold8 >> (16 * jj)));
                packed |= (u64)f2bf((1.f - zg) * n + zg * ho) << (16 * jj);
            }
            h_store8(hnxt + (size_t)bg * HH + jbase, packed);
        }

        asm volatile("s_waitcnt vmcnt(0)" ::: "memory");
        __syncthreads();
        if (tid == 0) flag_store(gflags + nt, (unsigned)(t + 1));

        if (t > 0)
            proj_tile<FRESH>(hcur, Woutb, out, pred, brow, it, wave, lane, lr, lk,
                             t - 1, boutv);
    }

    group_wait_busy(gflags, lane, (unsigned)TT);
    __syncthreads();
    proj_tile<FRESH>(hbuf + (size_t)(FRESH ? TT : (TT % 3)) * BBHH,
                     Woutb, out, pred, brow, it, wave, lane, lr, lk, TT - 1, boutv);
}

__global__ __launch_bounds__(256, 1) void dec12(
    const float* __restrict__ tgt, const us* __restrict__ Wperm,
    const float* __restrict__ bihp, const float* __restrict__ bhhp,
    us* hbuf, const us* __restrict__ Woutb,
    const float* __restrict__ bout, float* __restrict__ out,
    unsigned* flags, int fresh) {
    __shared__ float red[4][32 * RP2];
    __shared__ float gxn[32 * GP2];
    __shared__ float pred[3][16 * PP];
    if (fresh)
        run12<1>(tgt, Wperm, bihp, bhhp, hbuf, Woutb, bout, out, flags, red, gxn, pred);
    else
        run12<0>(tgt, Wperm, bihp, bhhp, hbuf, Woutb, bout, out, flags, red, gxn, pred);
}

// ---- diagnostic: ambient shader-clock probe ----
// Low-power spin until clock64() advances 24M shader ticks.
// dur_us = 24e6 / f_shader: 10ms @2.4GHz, ~48ms @500MHz. Always top-5 visible.
__global__ __launch_bounds__(64) void abl_clkprobe(float* sink) {
    long long t0 = clock64();
    while (clock64() - t0 < 24000000LL)
        __builtin_amdgcn_s_sleep(8);
    if (threadIdx.x == 0) sink[blockIdx.x] = (float)(clock64() - t0);
}

extern "C" void kernel_launch(void* const* d_in, const int* in_sizes, int n_in,
                              void* d_out, int out_size, void* d_ws, size_t ws_size,
                              hipStream_t stream) {
    const float* z    = (const float*)d_in[0];
    const float* tgt  = (const float*)d_in[2];
    const float* Wz2h = (const float*)d_in[3];
    const float* bz2h = (const float*)d_in[4];
    const float* Wih  = (const float*)d_in[5];
    const float* Whh  = (const float*)d_in[6];
    const float* bih  = (const float*)d_in[7];
    const float* bhh  = (const float*)d_in[8];
    const float* Wout = (const float*)d_in[9];
    const float* bout = (const float*)d_in[10];
    float* out = (float*)d_out;

    char* ws = (char*)d_ws;
    us* Wperm        = (us*)ws;                          // 7,864,320
    float* bihp      = (float*)(ws + 7864320);           //    12,288
    float* bhhp      = (float*)(ws + 7876608);           //    12,288
    us* Woutb        = (us*)(ws + 7888896);              //   524,288
    unsigned* flags  = (unsigned*)(ws + 8413184);        //     2,048 (8 grp x 64 words)
    float* sink      = (float*)(ws + 8415232);           //     2,048 (probe sink)
    us* hbuf         = (us*)(ws + 8417280);              // 257 or 3 slots x 524,288

    const size_t slotB = (size_t)BBHH * 2;
    const size_t need_big = 8417280ull + 257ull * slotB;
    const int fresh = (ws_size >= need_big) ? 1 : 0;

    hipMemsetAsync((void*)flags, 0, 2048, stream);
    hipLaunchKernelGGL(k_prep_w, dim3(GN), dim3(256), 0, stream, Whh, Wih, Wperm);
    hipLaunchKernelGGL(k_prep_misc, dim3(1024), dim3(256), 0, stream, bih, bhh, Wout,
                       bihp, bhhp, Woutb);
    hipLaunchKernelGGL(k_h0, dim3(BB), dim3(256), 0, stream, z, Wz2h, bz2h, hbuf);
    hipLaunchKernelGGL(dec12, dim3(256), dim3(256), 0, stream,
                       tgt, Wperm, bihp, bhhp, hbuf, Woutb, bout, out, flags, fresh);
    // ambient-clock probe AFTER the main kernel (inherits its DVFS regime)
    hipLaunchKernelGGL(abl_clkprobe, dim3(1), dim3(64), 0, stream, sink);
}

// Round 13
// 4960.791 us; speedup vs baseline: 3.1830x; 3.1830x over previous
//
#include <hip/hip_runtime.h>

#define BB 256
#define TT 256
#define II 256
#define HH 1024
#define LL 128
#define K1 1280   // HH + II
#define GN 3072   // 3*HH
#define BBHH (BB * HH)

#define PP 20     // pred row stride
// dynamic LDS layout (bytes): hlds 65536 | red 2*32*49*4=12544 | gxn 32*33*4=4224 | pred 3*16*20*4=3840
#define OFF_RED 65536
#define OFF_GXN (65536 + 12544)
#define OFF_PRED (65536 + 12544 + 4224)
#define LDS_TOTAL (65536 + 12544 + 4224 + 3840)

typedef short s8v    __attribute__((ext_vector_type(8)));
typedef float f32x4  __attribute__((ext_vector_type(4)));
typedef float f4v    __attribute__((ext_vector_type(4)));
typedef unsigned long long u64;
typedef unsigned short us;

__device__ __forceinline__ us f2bf(float f) {
    unsigned u = __float_as_uint(f);
    u += 0x7fffu + ((u >> 16) & 1u);
    return (us)(u >> 16);
}
__device__ __forceinline__ float bf2f(us h) {
    return __uint_as_float(((unsigned)h) << 16);
}
__device__ __forceinline__ float sigm(float x) { return 1.0f / (1.0f + __expf(-x)); }

__device__ __forceinline__ s8v cvt8(const float* __restrict__ p) {
    const f4v lo = *(const f4v*)p;
    const f4v hi = *(const f4v*)(p + 4);
    s8v r;
    r[0] = (short)f2bf(lo[0]); r[1] = (short)f2bf(lo[1]);
    r[2] = (short)f2bf(lo[2]); r[3] = (short)f2bf(lo[3]);
    r[4] = (short)f2bf(hi[0]); r[5] = (short)f2bf(hi[1]);
    r[6] = (short)f2bf(hi[2]); r[7] = (short)f2bf(hi[3]);
    return r;
}

__device__ __forceinline__ s8v hload16a(const us* p) {
    union { u64 q[2]; s8v v; } u;
    u.q[0] = __hip_atomic_load((const u64*)p, __ATOMIC_RELAXED, __HIP_MEMORY_SCOPE_AGENT);
    u.q[1] = __hip_atomic_load((const u64*)p + 1, __ATOMIC_RELAXED, __HIP_MEMORY_SCOPE_AGENT);
    return u.v;
}
template<int FRESH> __device__ __forceinline__ s8v ld16h(const us* p) {
    if constexpr (FRESH) return *(const s8v*)p;   // fresh slot addr: never stale
    else return hload16a(p);
}
__device__ __forceinline__ void h_store8(us* p, u64 v) {
    __hip_atomic_store((u64*)p, v, __ATOMIC_RELAXED, __HIP_MEMORY_SCOPE_AGENT);
}
__device__ __forceinline__ void flag_store(unsigned* p, unsigned v) {
    __hip_atomic_store(p, v, __ATOMIC_RELAXED, __HIP_MEMORY_SCOPE_AGENT);
}
__device__ __forceinline__ unsigned flag_probe(unsigned* p) {
    return __hip_atomic_load(p, __ATOMIC_RELAXED, __HIP_MEMORY_SCOPE_AGENT);
}
// busy group barrier: all waves; dependent-FMA burst between probes
__device__ __forceinline__ void group_wait_busy(unsigned* gf, int lane, unsigned t) {
    if (t == 0) return;
    float busy = (float)lane * 0.015625f + 1.0f;
    int guard = 0;
    for (;;) {
        unsigned v = t;
        if (lane < 32) v = flag_probe(gf + lane);
        if (__ballot(v >= t) == ~0ull) break;
#pragma unroll
        for (int i = 0; i < 64; ++i)
            busy = __builtin_fmaf(busy, 1.0000001f, 1e-9f);
        asm volatile("" :: "v"(busy));
        if (++guard > (1 << 17)) break;
    }
    asm volatile("" ::: "memory");
}

// ---- prep: permuted gate weights, 96-row blocks per nt (unchanged) ----
__global__ void k_prep_w(const float* __restrict__ Whh, const float* __restrict__ Wih,
                         us* __restrict__ Wperm) {
    int o = blockIdx.x;                 // 3072
    int ntt = o / 96, q = o - ntt * 96;
    int gate = q >> 5, jj = q & 31;
    int src = gate * HH + ntt * 32 + jj;
    const float* sh = Whh + (size_t)src * HH;
    const float* si = Wih + (size_t)src * II;
    us* dst = Wperm + (size_t)o * K1;
    for (int k = threadIdx.x; k < K1; k += 256)
        dst[k] = f2bf(k < HH ? sh[k] : si[k - HH]);
}

__global__ void k_prep_misc(const float* __restrict__ bih, const float* __restrict__ bhh,
                            const float* __restrict__ Wout,
                            float* __restrict__ bihp, float* __restrict__ bhhp,
                            us* __restrict__ Woutb) {
    int idx = blockIdx.x * 256 + threadIdx.x;
    if (idx < GN) {
        int ntt = idx / 96, q = idx - ntt * 96;
        int gate = q >> 5, jj = q & 31;
        int src = gate * HH + ntt * 32 + jj;
        bihp[idx] = bih[src];
        bhhp[idx] = bhh[src];
    }
    for (size_t i = (size_t)blockIdx.x * 256 + threadIdx.x; i < (size_t)II * HH;
         i += (size_t)gridDim.x * 256)
        Woutb[i] = f2bf(Wout[i]);
}

__global__ void k_h0(const float* __restrict__ z, const float* __restrict__ Wz,
                     const float* __restrict__ bz, us* __restrict__ hbuf) {
    int b = blockIdx.x;
    int j0 = threadIdx.x * 4;
    const f4v* zr = (const f4v*)(z + (size_t)b * LL);
    u64 packed = 0;
#pragma unroll
    for (int jj = 0; jj < 4; ++jj) {
        int j = j0 + jj;
        const f4v* wr = (const f4v*)(Wz + (size_t)j * LL);
        float s = bz[j];
#pragma unroll
        for (int i = 0; i < LL / 4; ++i) {
            f4v a = zr[i], w = wr[i];
            s += a[0] * w[0] + a[1] * w[1] + a[2] * w[2] + a[3] * w[3];
        }
        packed |= (u64)f2bf(tanhf(s)) << (16 * jj);
    }
    *(u64*)(hbuf + (size_t)b * HH + j0) = packed;
}

// ---- cooperative h stage: 32 rows x 1024 bf16 -> LDS, XOR-swizzled ----
// 16 independent 16B loads per thread (max MLP), then 16 ds_writes.
template<int FRESH>
__device__ __forceinline__ void stage_h(char* hl, const us* __restrict__ src, int tid) {
    s8v tmp[16];
#pragma unroll
    for (int i = 0; i < 16; ++i) {
        int c = i * 256 + tid;
        int row = c >> 7, c16 = c & 127;
        tmp[i] = ld16h<FRESH>(src + (size_t)row * HH + c16 * 8);
    }
#pragma unroll
    for (int i = 0; i < 16; ++i) {
        int c = i * 256 + tid;
        int row = c >> 7, c16 = c & 127;
        *(s8v*)(hl + (row << 11) + ((c16 << 4) ^ ((row & 7) << 4))) = tmp[i];
    }
}
// swizzled LDS A-read: row in [0,32), kElem multiple of 8
__device__ __forceinline__ s8v lds_a(const char* hl, int row, int kElem) {
    return *(const s8v*)(hl + (row << 11) + (((kElem << 1)) ^ ((row & 7) << 4)));
}

// h-part GEMM from LDS (NKS k-chunks of 32 starting at kbase)
template<int NKS>
__device__ __forceinline__ void gemm_h(const char* hl, const us* __restrict__ Wperm,
                                       int kbase, int lr, int lk, int obch, f32x4* acc) {
#pragma unroll
    for (int ks = 0; ks < NKS; ++ks) {
        const int k = kbase + ks * 32 + lk;
        s8v a[2], w[3];
#pragma unroll
        for (int mi = 0; mi < 2; ++mi)
            a[mi] = lds_a(hl, mi * 16 + lr, k);
#pragma unroll
        for (int ni = 0; ni < 3; ++ni)
            w[ni] = *(const s8v*)(Wperm + (size_t)(obch + ni * 16 + lr) * K1 + k);
#pragma unroll
        for (int mi = 0; mi < 2; ++mi)
#pragma unroll
            for (int ni = 0; ni < 3; ++ni)
                acc[mi * 3 + ni] = __builtin_amdgcn_mfma_f32_16x16x32_bf16(
                    a[mi], w[ni], acc[mi * 3 + ni], 0, 0, 0);
    }
}

// projection from LDS h: one 16x16 tile, K=1024 split across 4 waves
__device__ __forceinline__ void proj_lds(
    const char* hl, const us* __restrict__ Woutb, float* __restrict__ out,
    float (*pred)[16 * PP], int brow, int lrow0, int it,
    int wave, int lane, int lr, int lk, int tp, float boutv) {
    f32x4 oa = {0.f, 0.f, 0.f, 0.f};
    const int lrow = lrow0 + lr;
    const us* wp = Woutb + (size_t)(it * 16 + lr) * HH + (wave << 8) + lk;
#pragma unroll
    for (int ks = 0; ks < 8; ++ks) {
        s8v a = lds_a(hl, lrow, (wave << 8) + ks * 32 + lk);
        s8v w = *(const s8v*)(wp + ks * 32);
        oa = __builtin_amdgcn_mfma_f32_16x16x32_bf16(a, w, oa, 0, 0, 0);
    }
    if (wave >= 1) {
#pragma unroll
        for (int r = 0; r < 4; ++r)
            pred[wave - 1][(((lane >> 4) << 2) + r) * PP + lr] = oa[r];
    }
    __syncthreads();
    if (wave == 0) {
#pragma unroll
        for (int r = 0; r < 4; ++r) {
            int rw = ((lane >> 4) << 2) + r;
            int idx = rw * PP + lr;
            float v = oa[r] + pred[0][idx] + pred[1][idx] + pred[2][idx] + boutv;
            out[(size_t)(brow + rw) * (TT * II) + (size_t)tp * II + it * 16 + lr] = sigm(v);
        }
    }
    __syncthreads();
}

// ---- main loop: nt-major XCD mapping; 8 groups x 32 batches; 2x2 wave split ----
template<int FRESH>
__device__ void run13(const float* __restrict__ tgt, const us* __restrict__ Wperm,
                      const float* __restrict__ bihp, const float* __restrict__ bhhp,
                      us* hbuf, const us* __restrict__ Woutb,
                      const float* __restrict__ bout, float* __restrict__ out,
                      unsigned* flags, char* smem) {
    char* hl = smem;
    float* red = (float*)(smem + OFF_RED);    // [2][32*49]
    float* gxn = (float*)(smem + OFF_GXN);    // [32*33]
    float (*pred)[16 * PP] = (float(*)[16 * PP])(smem + OFF_PRED);

    const int tid = threadIdx.x;
    const int wave = tid >> 6, lane = tid & 63;
    const int kh = wave >> 1, ch = wave & 1;
    const int lr = lane & 15;
    const int lk = (lane >> 4) << 3;
    const int hi4 = ((lane >> 4) << 2);
    const int bid = blockIdx.x;
    const int x = bid & 7, q = (bid >> 3) & 3, g = bid >> 5;
    const int nt = x * 4 + q;
    const int lrow0 = (nt >> 4) * 16, it = nt & 15;
    const int brow = g * 32 + lrow0;
    const float boutv = bout[it * 16 + lr];
    const int ob = nt * 96;
    const int obch = ob + ch * 48;

    // epilogue ownership: batch eb (0..31), 4 j at jq*4
    const int eb = tid & 31, jq = tid >> 5;
    float bir[4], biz[4], bixn[4], bihn[4];
#pragma unroll
    for (int jj = 0; jj < 4; ++jj) {
        int j = jq * 4 + jj;
        bir[jj]  = bihp[ob + j] + bhhp[ob + j];
        biz[jj]  = bihp[ob + 32 + j] + bhhp[ob + 32 + j];
        bixn[jj] = bihp[ob + 64 + j];
        bihn[jj] = bhhp[ob + 64 + j];
    }

    unsigned* gflags = flags + (g << 6);

    for (int t = 0; t < TT; ++t) {
        const us* hcur = hbuf + (size_t)(FRESH ? t : (t % 3)) * BBHH;
        us* hnxt = hbuf + (size_t)(FRESH ? (t + 1) : ((t + 1) % 3)) * BBHH;

        f32x4 acc[6];
#pragma unroll
        for (int i = 0; i < 6; ++i) acc[i] = (f32x4){0.f, 0.f, 0.f, 0.f};

        // kh=1 waves: x-part GEMM BEFORE the barrier (k' in [0,256))
        if (kh == 1) {
            f32x4 accx[4];
#pragma unroll
            for (int i = 0; i < 4; ++i) accx[i] = (f32x4){0.f, 0.f, 0.f, 0.f};
#pragma unroll
            for (int ks = 0; ks < 8; ++ks) {
                const int kx = ks * 32 + lk;
                s8v xa[2], w[3];
#pragma unroll
                for (int mi = 0; mi < 2; ++mi)
                    xa[mi] = cvt8(tgt + ((size_t)(g * 32 + mi * 16 + lr) * TT + t) * II + kx);
#pragma unroll
                for (int ni = 0; ni < 3; ++ni)
                    w[ni] = *(const s8v*)(Wperm + (size_t)(obch + ni * 16 + lr) * K1 + HH + kx);
                if (ch == 0) {
#pragma unroll
                    for (int mi = 0; mi < 2; ++mi)
#pragma unroll
                        for (int ni = 0; ni < 3; ++ni)
                            acc[mi * 3 + ni] = __builtin_amdgcn_mfma_f32_16x16x32_bf16(
                                xa[mi], w[ni], acc[mi * 3 + ni], 0, 0, 0);
                } else {
#pragma unroll
                    for (int mi = 0; mi < 2; ++mi) {
                        acc[mi * 3 + 0] = __builtin_amdgcn_mfma_f32_16x16x32_bf16(
                            xa[mi], w[0], acc[mi * 3 + 0], 0, 0, 0);
                        accx[mi * 2 + 0] = __builtin_amdgcn_mfma_f32_16x16x32_bf16(
                            xa[mi], w[1], accx[mi * 2 + 0], 0, 0, 0);
                        accx[mi * 2 + 1] = __builtin_amdgcn_mfma_f32_16x16x32_bf16(
                            xa[mi], w[2], accx[mi * 2 + 1], 0, 0, 0);
                    }
                }
            }
            if (ch == 1) {
#pragma unroll
                for (int mi = 0; mi < 2; ++mi)
#pragma unroll
                    for (int n2 = 0; n2 < 2; ++n2)
#pragma unroll
                        for (int r = 0; r < 4; ++r)
                            gxn[(mi * 16 + hi4 + r) * 33 + n2 * 16 + lr] = accx[mi * 2 + n2][r];
            }
        }

        // barrier: all 32 group members published h_t
        group_wait_busy(gflags, lane, (unsigned)t);
        __syncthreads();

        // cooperative h stage -> LDS (the latency fix: 16 independent loads/thread)
        stage_h<FRESH>(hl, hcur + (size_t)(g * 32) * HH, tid);
        __syncthreads();

        // h-part GEMM from LDS
        if (kh == 0) gemm_h<20>(hl, Wperm, 0, lr, lk, obch, acc);
        else         gemm_h<12>(hl, Wperm, 640, lr, lk, obch, acc);

        // reduce: kh=1 writes, kh=0 adds
        {
            float* rc = red + ch * (32 * 49);
            if (kh == 1) {
#pragma unroll
                for (int mi = 0; mi < 2; ++mi)
#pragma unroll
                    for (int ni = 0; ni < 3; ++ni)
#pragma unroll
                        for (int r = 0; r < 4; ++r)
                            rc[(mi * 16 + hi4 + r) * 49 + ni * 16 + lr] = acc[mi * 3 + ni][r];
            }
            __syncthreads();
            if (kh == 0) {
#pragma unroll
                for (int mi = 0; mi < 2; ++mi)
#pragma unroll
                    for (int ni = 0; ni < 3; ++ni)
#pragma unroll
                        for (int r = 0; r < 4; ++r) {
                            int idx = (mi * 16 + hi4 + r) * 49 + ni * 16 + lr;
                            rc[idx] += acc[mi * 3 + ni][r];
                        }
            }
            __syncthreads();
        }

        // gate epilogue: thread (eb, jq*4..+3); h_old from LDS; one 8B sc1 store
        {
            const int bg = g * 32 + eb;
            const int jbase = nt * 32 + jq * 4;
            u64 hold8 = *(const u64*)(hl + (eb << 11) +
                            (((nt << 6) + (jq << 3)) ^ ((eb & 7) << 4)));
            u64 packed = 0;
#pragma unroll
            for (int jj = 0; jj < 4; ++jj) {
                int j = jq * 4 + jj;
                float ghr = red[eb * 49 + j];
                float ghz = (j < 16) ? red[eb * 49 + 32 + j]
                                     : red[1568 + eb * 49 + (j - 16)];
                float ghn = red[1568 + eb * 49 + 16 + j];
                float gx  = gxn[eb * 33 + j];
                float r   = sigm(ghr + bir[jj]);
                float zg  = sigm(ghz + biz[jj]);
                float n   = tanhf(gx + bixn[jj] + r * (ghn + bihn[jj]));
                float ho  = bf2f((us)(hold8 >> (16 * jj)));
                packed |= (u64)f2bf((1.f - zg) * n + zg * ho) << (16 * jj);
            }
            h_store8(hnxt + (size_t)bg * HH + jbase, packed);
        }

        // arrive: drain sc1 stores, signal
        asm volatile("s_waitcnt vmcnt(0)" ::: "memory");
        __syncthreads();
        if (tid == 0) flag_store(gflags + nt, (unsigned)(t + 1));

        // project y_{t-1} from LDS-resident h_t while peers' flags propagate
        if (t > 0)
            proj_lds(hl, Woutb, out, pred, brow, lrow0, it, wave, lane, lr, lk,
                     t - 1, boutv);
    }

    // tail: stage h_T, project y_{T-1}
    group_wait_busy(gflags, lane, (unsigned)TT);
    __syncthreads();
    stage_h<FRESH>(hl, hbuf + (size_t)(FRESH ? TT : (TT % 3)) * BBHH + (size_t)(g * 32) * HH, tid);
    __syncthreads();
    proj_lds(hl, Woutb, out, pred, brow, lrow0, it, wave, lane, lr, lk, TT - 1, boutv);
}

__global__ __launch_bounds__(256, 1) void dec13(
    const float* __restrict__ tgt, const us* __restrict__ Wperm,
    const float* __restrict__ bihp, const float* __restrict__ bhhp,
    us* hbuf, const us* __restrict__ Woutb,
    const float* __restrict__ bout, float* __restrict__ out,
    unsigned* flags, int fresh) {
    extern __shared__ char smem[];
    if (fresh)
        run13<1>(tgt, Wperm, bihp, bhhp, hbuf, Woutb, bout, out, flags, smem);
    else
        run13<0>(tgt, Wperm, bihp, bhhp, hbuf, Woutb, bout, out, flags, smem);
}

extern "C" void kernel_launch(void* const* d_in, const int* in_sizes, int n_in,
                              void* d_out, int out_size, void* d_ws, size_t ws_size,
                              hipStream_t stream) {
    const float* z    = (const float*)d_in[0];
    const float* tgt  = (const float*)d_in[2];
    const float* Wz2h = (const float*)d_in[3];
    const float* bz2h = (const float*)d_in[4];
    const float* Wih  = (const float*)d_in[5];
    const float* Whh  = (const float*)d_in[6];
    const float* bih  = (const float*)d_in[7];
    const float* bhh  = (const float*)d_in[8];
    const float* Wout = (const float*)d_in[9];
    const float* bout = (const float*)d_in[10];
    float* out = (float*)d_out;

    char* ws = (char*)d_ws;
    us* Wperm        = (us*)ws;                          // 7,864,320
    float* bihp      = (float*)(ws + 7864320);           //    12,288
    float* bhhp      = (float*)(ws + 7876608);           //    12,288
    us* Woutb        = (us*)(ws + 7888896);              //   524,288
    unsigned* flags  = (unsigned*)(ws + 8413184);        //     2,048 (8 grp x 64 words)
    us* hbuf         = (us*)(ws + 8415232);              // 257 or 3 slots x 524,288

    const size_t slotB = (size_t)BBHH * 2;
    const size_t need_big = 8415232ull + 257ull * slotB;
    const int fresh = (ws_size >= need_big) ? 1 : 0;

    hipMemsetAsync((void*)flags, 0, 2048, stream);
    hipLaunchKernelGGL(k_prep_w, dim3(GN), dim3(256), 0, stream, Whh, Wih, Wperm);
    hipLaunchKernelGGL(k_prep_misc, dim3(1024), dim3(256), 0, stream, bih, bhh, Wout,
                       bihp, bhhp, Woutb);
    hipLaunchKernelGGL(k_h0, dim3(BB), dim3(256), 0, stream, z, Wz2h, bz2h, hbuf);

    hipFuncSetAttribute((const void*)dec13,
                        hipFuncAttributeMaxDynamicSharedMemorySize, LDS_TOTAL);
    hipLaunchKernelGGL(dec13, dim3(256), dim3(256), LDS_TOTAL, stream,
                       tgt, Wperm, bihp, bhhp, hbuf, Woutb, bout, out, flags, fresh);
}